// Round 16
// baseline (197.420 us; speedup 1.0000x reference)
//
#include <hip/hip_runtime.h>
#include <math.h>

#define D_INN 256
#define D_HID 64
#define DTR 16
#define D_MEMM 128
#define BB 2
#define LL 2048
#define NROWS (BB*LL)   // 4096
#define NPROJ 736
#define NTOT 864        // 736 proj cols + 128 Q cols
#define SEG 16
#define SEGLEN (LL/SEG) // 128
#define NCHUNK (LL/8)   // 256 8-step chunks per batch

typedef __attribute__((ext_vector_type(8))) short short8v;
typedef __attribute__((ext_vector_type(4))) float float4v;

static __device__ __forceinline__ unsigned short f2bf(float f) {
    unsigned int u = __float_as_uint(f);
    u += 0x7fff + ((u >> 16) & 1);   // RNE
    return (unsigned short)(u >> 16);
}

// packed index: (((g*BB + b)*NCHUNK + chunk)*64 + n)*8 + li   (g: 0=B, 1=Bl, 2=C)
#define PK(g, b, chunk, n, li) (((((size_t)(g)*BB + (b)) * NCHUNK + (chunk)) * 64 + (n)) * 8 + (li))

// ---------------- Kernel 1: proj = x @ [W_xproj | W_Q] (+b_Q), bf16 MFMA ----------------
__global__ __launch_bounds__(256) void k_gemm(const float* __restrict__ x,
        const float* __restrict__ Wx, const float* __restrict__ Wq,
        const float* __restrict__ bq, float* __restrict__ proj,
        float* __restrict__ packed) {
    __shared__ unsigned short As[64][40];
    __shared__ unsigned short Bs[64][40];
    const int t = threadIdx.x;
    const int lane = t & 63, w = t >> 6;
    const int wr = w >> 1, wc = w & 1;
    const int row0 = blockIdx.y * 64, col0 = blockIdx.x * 64;

    float4v acc[2][2];
    #pragma unroll
    for (int i = 0; i < 2; i++)
        #pragma unroll
        for (int j = 0; j < 2; j++) acc[i][j] = (float4v)0.f;

    const int ar = t >> 2, akq = (t & 3) * 8;
    const int bk = t >> 3, bcq = (t & 7) * 8;

    for (int k0 = 0; k0 < D_INN; k0 += 32) {
        float4 a0 = *(const float4*)&x[(size_t)(row0 + ar) * D_INN + k0 + akq];
        float4 a1 = *(const float4*)&x[(size_t)(row0 + ar) * D_INN + k0 + akq + 4];
        float4 b0 = {}, b1 = {};
        int col = col0 + bcq;
        if (col + 8 <= NPROJ) {
            b0 = *(const float4*)&Wx[(size_t)(k0 + bk) * NPROJ + col];
            b1 = *(const float4*)&Wx[(size_t)(k0 + bk) * NPROJ + col + 4];
        } else if (col < NTOT) {
            b0 = *(const float4*)&Wq[(size_t)(k0 + bk) * D_MEMM + (col - NPROJ)];
            b1 = *(const float4*)&Wq[(size_t)(k0 + bk) * D_MEMM + (col - NPROJ) + 4];
        }
        __syncthreads();
        {
            unsigned short av[8] = { f2bf(a0.x), f2bf(a0.y), f2bf(a0.z), f2bf(a0.w),
                                     f2bf(a1.x), f2bf(a1.y), f2bf(a1.z), f2bf(a1.w) };
            *(short8v*)&As[ar][akq] = *(short8v*)av;
            Bs[bcq + 0][bk] = f2bf(b0.x); Bs[bcq + 1][bk] = f2bf(b0.y);
            Bs[bcq + 2][bk] = f2bf(b0.z); Bs[bcq + 3][bk] = f2bf(b0.w);
            Bs[bcq + 4][bk] = f2bf(b1.x); Bs[bcq + 5][bk] = f2bf(b1.y);
            Bs[bcq + 6][bk] = f2bf(b1.z); Bs[bcq + 7][bk] = f2bf(b1.w);
        }
        __syncthreads();
        short8v af[2], bf[2];
        const int fr = lane & 15, fk = (lane >> 4) * 8;
        af[0] = *(short8v*)&As[wr * 32 + fr][fk];
        af[1] = *(short8v*)&As[wr * 32 + 16 + fr][fk];
        bf[0] = *(short8v*)&Bs[wc * 32 + fr][fk];
        bf[1] = *(short8v*)&Bs[wc * 32 + 16 + fr][fk];
        #pragma unroll
        for (int i = 0; i < 2; i++)
            #pragma unroll
            for (int j = 0; j < 2; j++)
                acc[i][j] = __builtin_amdgcn_mfma_f32_16x16x32_bf16(af[i], bf[j], acc[i][j], 0, 0, 0);
    }
    #pragma unroll
    for (int i = 0; i < 2; i++)
        #pragma unroll
        for (int j = 0; j < 2; j++) {
            int cc = col0 + wc * 32 + j * 16 + (lane & 15);
            int rr0 = row0 + wr * 32 + i * 16 + (lane >> 4) * 4;
            if (cc < 192) {   // B / Bl / C -> packed layout
                int g = cc >> 6, n = cc & 63;
                int bb = rr0 >> 11, l = rr0 & (LL - 1);
                float4 pk = make_float4(acc[i][j][0], acc[i][j][1], acc[i][j][2], acc[i][j][3]);
                *(float4*)&packed[PK(g, bb, l >> 3, n, l & 7)] = pk;
            } else {
                #pragma unroll
                for (int e = 0; e < 4; e++) {
                    float v = acc[i][j][e];
                    if (cc >= NPROJ) v += bq[cc - NPROJ];
                    proj[(size_t)(rr0 + e) * NTOT + cc] = v;
                }
            }
        }
}

// ---------------- Kernel 2: prep = {delta/p/csum transposed | x transpose} ----------------
__global__ __launch_bounds__(256) void k_prep(const float* __restrict__ x,
        const float* __restrict__ proj,
        const float* __restrict__ Wdt, const float* __restrict__ bdt,
        const float* __restrict__ Wdtl, const float* __restrict__ bdtl,
        float* __restrict__ deltaT, float* __restrict__ deltalT,
        float* __restrict__ pT0, float* __restrict__ pT1,
        float* __restrict__ csum0, float* __restrict__ csum1,
        float* __restrict__ xT) {
    __shared__ float sh[64 * 66];
    const int t = threadIdx.x;
    if (blockIdx.y == 0) {
        float (*sdt)[17]  = (float(*)[17])sh;
        float (*sdtl)[17] = (float(*)[17])(sh + 16 * 17);
        const int r0 = blockIdx.x * 16;
        const int b = r0 >> 11, l0 = r0 & (LL - 1);
        {
            int r = t >> 4, c = t & 15;
            sdt[r][c]  = proj[(size_t)(r0 + r) * NTOT + 704 + c];
            sdtl[r][c] = proj[(size_t)(r0 + r) * NTOT + 720 + c];
        }
        __syncthreads();
        float w1[DTR], w2[DTR];
        #pragma unroll
        for (int r = 0; r < DTR; r++) {
            w1[r] = Wdt[r * D_INN + t];
            w2[r] = Wdtl[r * D_INN + t];
        }
        const float b1 = bdt[t], b2 = bdtl[t];
        float o1[16], o2[16], q1[16], q2[16];
        #pragma unroll
        for (int row = 0; row < 16; ++row) {
            float a1 = b1, a2 = b2;
            #pragma unroll
            for (int r = 0; r < DTR; r++) {
                a1 += sdt[row][r] * w1[r];
                a2 += sdtl[row][r] * w2[r];
            }
            o1[row] = (a1 > 20.f) ? a1 : log1pf(expf(a1));
            o2[row] = (a2 > 20.f) ? a2 : log1pf(expf(a2));
            float xv = x[(size_t)(r0 + row) * D_INN + t];
            q1[row] = o1[row] * xv;
            q2[row] = o2[row] * xv;
        }
        float* d1 = &deltaT[((size_t)b * D_INN + t) * LL + l0];
        float* d2 = &deltalT[((size_t)b * D_INN + t) * LL + l0];
        float* p1 = &pT0[((size_t)b * D_INN + t) * LL + l0];
        float* p2 = &pT1[((size_t)b * D_INN + t) * LL + l0];
        #pragma unroll
        for (int j = 0; j < 16; j += 4) {
            *(float4*)&d1[j] = make_float4(o1[j], o1[j+1], o1[j+2], o1[j+3]);
            *(float4*)&d2[j] = make_float4(o2[j], o2[j+1], o2[j+2], o2[j+3]);
            *(float4*)&p1[j] = make_float4(q1[j], q1[j+1], q1[j+2], q1[j+3]);
            *(float4*)&p2[j] = make_float4(q2[j], q2[j+1], q2[j+2], q2[j+3]);
        }
        // per-chunk delta sums (2 chunks per thread)
        float c0a = 0.f, c0b = 0.f, c1a = 0.f, c1b = 0.f;
        #pragma unroll
        for (int j = 0; j < 8; ++j) { c0a += o1[j]; c0b += o1[8 + j];
                                      c1a += o2[j]; c1b += o2[8 + j]; }
        size_t cbase = ((size_t)b * D_INN + t) * NCHUNK + (l0 >> 3);
        csum0[cbase] = c0a; csum0[cbase + 1] = c0b;
        csum1[cbase] = c1a; csum1[cbase + 1] = c1b;
    } else {
        float (*tile)[65] = (float(*)[65])sh;
        const int bx = blockIdx.x;
        const int lt = (bx & 31) * 64, dt = ((bx >> 5) & 3) * 64, b = bx >> 7;
        const int c = t & 63, rg = (t >> 6) * 16;
        #pragma unroll
        for (int j = 0; j < 16; ++j)
            tile[rg + j][c] = x[((size_t)b * LL + lt + rg + j) * D_INN + dt + c];
        __syncthreads();
        #pragma unroll
        for (int j = 0; j < 16; ++j)
            xT[((size_t)b * D_INN + dt + rg + j) * LL + lt + c] = tile[c][rg + j];
    }
}

// ---------------- Kernel 3A: both scans' pass 1 — wave-uniform δ/p loads, no shuffles ----
// grid (64, 2, 16); block 256 = 4 waves; wave w -> d = d0+w, lane n.
__global__ __launch_bounds__(256) void k_scanA(
        const float* __restrict__ packed, const float* __restrict__ A,
        const float* __restrict__ deltaT, const float* __restrict__ deltalT,
        const float* __restrict__ pT0, const float* __restrict__ pT1,
        const float* __restrict__ csum0, const float* __restrict__ csum1,
        float* __restrict__ Qbuf, float* __restrict__ SDbuf,
        float* __restrict__ cumd, float* __restrict__ mem) {
    const int t = threadIdx.x, w = t >> 6, n = t & 63;
    const int b = blockIdx.y, seg = blockIdx.z;
    const int d = blockIdx.x * 4 + w;
    const float Aln = A[d * D_HID + n] * 1.44269504f;
    const size_t base = ((size_t)b * D_INN + d) * LL + seg * SEGLEN;
    const float* dT0 = deltaT + base;
    const float* dT1 = deltalT + base;
    const float* pp0 = pT0 + base;
    const float* pp1 = pT1 + base;
    const float* Bp0 = packed + PK(0, b, seg * 16, 0, 0);
    const float* Bp1 = packed + PK(1, b, seg * 16, 0, 0);
    const size_t cbase = ((size_t)b * D_INN + d) * NCHUNK + seg * 16;

    float cum[8], part[8];
    float s0 = 0.f, s1 = 0.f, sd1 = 0.f;

    for (int c = 0; c < 16; ++c) {
        // wave-uniform loads (same address across lanes -> L1 broadcast)
        float4 d0a = *(const float4*)&dT0[c * 8], d0b = *(const float4*)&dT0[c * 8 + 4];
        float4 d1a = *(const float4*)&dT1[c * 8], d1b = *(const float4*)&dT1[c * 8 + 4];
        float4 p0a = *(const float4*)&pp0[c * 8], p0b = *(const float4*)&pp0[c * 8 + 4];
        float4 p1a = *(const float4*)&pp1[c * 8], p1b = *(const float4*)&pp1[c * 8 + 4];
        // per-lane B loads
        float4 B00 = *(const float4*)&Bp0[((size_t)c * 64 + n) * 8];
        float4 B01 = *(const float4*)&Bp0[((size_t)c * 64 + n) * 8 + 4];
        float4 B10 = *(const float4*)&Bp1[((size_t)c * 64 + n) * 8];
        float4 B11 = *(const float4*)&Bp1[((size_t)c * 64 + n) * 8 + 4];
        float dv0[8] = {d0a.x, d0a.y, d0a.z, d0a.w, d0b.x, d0b.y, d0b.z, d0b.w};
        float dv1[8] = {d1a.x, d1a.y, d1a.z, d1a.w, d1b.x, d1b.y, d1b.z, d1b.w};
        float pv0[8] = {p0a.x, p0a.y, p0a.z, p0a.w, p0b.x, p0b.y, p0b.z, p0b.w};
        float pv1[8] = {p1a.x, p1a.y, p1a.z, p1a.w, p1b.x, p1b.y, p1b.z, p1b.w};
        float Bv0[8] = {B00.x, B00.y, B00.z, B00.w, B01.x, B01.y, B01.z, B01.w};
        float Bv1[8] = {B10.x, B10.y, B10.z, B10.w, B11.x, B11.y, B11.z, B11.w};
        #pragma unroll
        for (int li = 0; li < 8; ++li) {
            s0 = fmaf(exp2f(dv0[li] * Aln), s0, pv0[li] * Bv0[li]);
            s1 = fmaf(exp2f(dv1[li] * Aln), s1, pv1[li] * Bv1[li]);
            if (li == 0 && (c & 1) == 0) {
                float v = s1;
                #pragma unroll
                for (int off = 32; off >= 1; off >>= 1) v += __shfl_xor(v, off);
                part[c >> 1] = v;
                cum[c >> 1] = sd1 + dv1[0];
            }
        }
        sd1 += csum1[cbase + c];
    }
    // sd0: total segment delta sum from chunk sums
    float sd0 = 0.f;
    {
        float4 ca = *(const float4*)&csum0[cbase];
        float4 cb = *(const float4*)&csum0[cbase + 4];
        float4 cc = *(const float4*)&csum0[cbase + 8];
        float4 cd = *(const float4*)&csum0[cbase + 12];
        sd0 = ((ca.x + ca.y) + (ca.z + ca.w)) + ((cb.x + cb.y) + (cb.z + cb.w))
            + ((cc.x + cc.y) + (cc.z + cc.w)) + ((cd.x + cd.y) + (cd.z + cd.w));
    }

    Qbuf[(((size_t)b * SEG + seg) * D_INN + d) * 64 + n] = s0;
    Qbuf[(((size_t)(2 + b) * SEG + seg) * D_INN + d) * 64 + n] = s1;
    if (n == 0) {
        SDbuf[((size_t)b * SEG + seg) * D_INN + d] = sd0;
        SDbuf[((size_t)(2 + b) * SEG + seg) * D_INN + d] = sd1;
        #pragma unroll
        for (int ck = 0; ck < 8; ++ck) {
            mem[((size_t)b * 128 + seg * 8 + ck) * D_INN + d] = part[ck];
            cumd[(((size_t)b * SEG + seg) * 8 + ck) * D_INN + d] = cum[ck];
        }
    }
}

// ---------------- Kernel 3B: prefix + pass 2 (scan0) + mem corrections (scan1) ----------
__global__ __launch_bounds__(256) void k_scanBC(const float* __restrict__ xT,
        const float* __restrict__ packed, const float* __restrict__ A,
        const float* __restrict__ Dp, const float* __restrict__ deltaT,
        const float* __restrict__ pT0,
        const float* __restrict__ Qbuf, const float* __restrict__ SDbuf,
        const float* __restrict__ cumd,
        float* __restrict__ y, float* __restrict__ mem) {
    __shared__ float rbuf[4][8][65];
    const int t = threadIdx.x, w = t >> 6, n = t & 63;
    const int b = blockIdx.y, seg = blockIdx.z;
    const int d = blockIdx.x * 4 + w;
    const int lr = n & 7, rli = n >> 3, g = n & 7;
    const float Aln = A[d * D_HID + n] * 1.44269504f;
    const float Dpv = Dp[d];
    const size_t rowbase = (size_t)b * LL + (size_t)seg * SEGLEN;
    const size_t base = ((size_t)b * D_INN + d) * LL + seg * SEGLEN;
    const float* uT  = xT + base;
    const float* dT0 = deltaT + base;
    const float* pp0 = pT0 + base;
    const float* Bp = packed + PK(0, b, seg * 16, 0, 0);
    const float* Cp = packed + PK(2, b, seg * 16, 0, 0);

    // prefix s_in for both scans
    float sin0 = 0.f, sin1 = 0.f;
    for (int k = 0; k < seg; ++k) {
        float sdk0 = SDbuf[((size_t)b * SEG + k) * D_INN + d];
        float qk0  = Qbuf[(((size_t)b * SEG + k) * D_INN + d) * 64 + n];
        sin0 = fmaf(exp2f(sdk0 * Aln), sin0, qk0);
        float sdk1 = SDbuf[((size_t)(2 + b) * SEG + k) * D_INN + d];
        float qk1  = Qbuf[(((size_t)(2 + b) * SEG + k) * D_INN + d) * 64 + n];
        sin1 = fmaf(exp2f(sdk1 * Aln), sin1, qk1);
    }

    // mem corrections for scan1 (seg > 0)
    if (seg > 0) {
        #pragma unroll
        for (int ck = 0; ck < 8; ++ck) {
            float cum = cumd[(((size_t)b * SEG + seg) * 8 + ck) * D_INN + d];
            float v = exp2f(cum * Aln) * sin1;
            #pragma unroll
            for (int off = 32; off >= 1; off >>= 1) v += __shfl_xor(v, off);
            if (n == 0) mem[((size_t)b * 128 + seg * 8 + ck) * D_INN + d] += v;
        }
    }

    // pass 2 for scan0: wave-uniform δ/p loads, ILP precompute
    float s = sin0;
    for (int c = 0; c < 16; ++c) {
        const size_t l0 = rowbase + c * 8;
        float4 d0a = *(const float4*)&dT0[c * 8], d0b = *(const float4*)&dT0[c * 8 + 4];
        float4 p0a = *(const float4*)&pp0[c * 8], p0b = *(const float4*)&pp0[c * 8 + 4];
        float uvl = uT[c * 8 + lr];   // per-lane, for the y epilogue shfl
        float4 B0 = *(const float4*)&Bp[((size_t)c * 64 + n) * 8];
        float4 B1 = *(const float4*)&Bp[((size_t)c * 64 + n) * 8 + 4];
        float4 C0 = *(const float4*)&Cp[((size_t)c * 64 + n) * 8];
        float4 C1 = *(const float4*)&Cp[((size_t)c * 64 + n) * 8 + 4];
        float dv[8] = {d0a.x, d0a.y, d0a.z, d0a.w, d0b.x, d0b.y, d0b.z, d0b.w};
        float pv[8] = {p0a.x, p0a.y, p0a.z, p0a.w, p0b.x, p0b.y, p0b.z, p0b.w};
        float Bv[8] = {B0.x, B0.y, B0.z, B0.w, B1.x, B1.y, B1.z, B1.w};
        float Cv[8] = {C0.x, C0.y, C0.z, C0.w, C1.x, C1.y, C1.z, C1.w};
        float dAr[8], pBr[8];
        #pragma unroll
        for (int li = 0; li < 8; ++li) {
            dAr[li] = exp2f(dv[li] * Aln);
            pBr[li] = pv[li] * Bv[li];
        }
        #pragma unroll
        for (int li = 0; li < 8; ++li) {
            s = fmaf(dAr[li], s, pBr[li]);
            rbuf[w][li][n] = s * Cv[li];
        }
        float acc = 0.f;
        #pragma unroll
        for (int j = 0; j < 8; ++j) acc += rbuf[w][rli][g * 8 + j];
        acc += __shfl_xor(acc, 1);
        acc += __shfl_xor(acc, 2);
        acc += __shfl_xor(acc, 4);
        float uv = __shfl(uvl, rli);   // outside the guard (all lanes active)
        if (g == 0) {
            y[(l0 + rli) * D_INN + d] = acc + uv * Dpv;
        }
    }
}

// ---------------- Kernel 4: fused K^T, V, VWo per memory row ----------------
__global__ __launch_bounds__(128) void k_kvwo(const float* __restrict__ mem,
        const float* __restrict__ Wk, const float* __restrict__ bk,
        const float* __restrict__ Wv, const float* __restrict__ bv,
        const float* __restrict__ Wo,
        float* __restrict__ KT, float* __restrict__ VWo) {
    __shared__ float mrow[256];
    __shared__ float vrow[128];
    const int k = blockIdx.x, b = blockIdx.y;
    const int t = threadIdx.x;
    const float* mr = mem + ((size_t)b * 128 + k) * D_INN;
    mrow[t] = mr[t];
    mrow[t + 128] = mr[t + 128];
    __syncthreads();
    float aK = bk[t], aV = bv[t];
    for (int dd = 0; dd < D_INN; dd++) {
        float m = mrow[dd];
        aK += m * Wk[dd * D_MEMM + t];
        aV += m * Wv[dd * D_MEMM + t];
    }
    KT[((size_t)b * 128 + t) * 128 + k] = aK;   // transposed store
    vrow[t] = aV;
    __syncthreads();
    float a0 = 0.f, a1 = 0.f;
    for (int m = 0; m < 128; ++m) {
        float vm = vrow[m];
        a0 += vm * Wo[(size_t)m * D_INN + t];
        a1 += vm * Wo[(size_t)m * D_INN + t + 128];
    }
    VWo[((size_t)b * 128 + k) * D_INN + t] = a0;
    VWo[((size_t)b * 128 + k) * D_INN + t + 128] = a1;
}

// ---------------- Kernel 5: attention + epilogue, 8 rows per block ----------------
__global__ __launch_bounds__(256) void k_attn(const float* __restrict__ x,
        const float* __restrict__ proj, const float* __restrict__ y,
        const float* __restrict__ KT, const float* __restrict__ VWo,
        const float* __restrict__ bo, float* __restrict__ out) {
    __shared__ float qs[8][132];
    __shared__ float ws[8][132];
    __shared__ float denom[8];
    const int t = threadIdx.x;
    const int b = blockIdx.y;
    const int r0 = blockIdx.x * 8;
    const size_t rowbase = (size_t)b * LL + r0;
    {
        int r = t >> 5, c4 = (t & 31) * 4;
        *(float4*)&qs[r][c4] = *(const float4*)&proj[(rowbase + r) * NTOT + NPROJ + c4];
    }
    __syncthreads();
    {
        const int kk = t & 127, rg = (t >> 7) * 4;
        const float* KTb = KT + (size_t)b * 128 * 128 + kk;
        float acc[4] = {};
        #pragma unroll 8
        for (int m = 0; m < 128; m += 4) {
            float k0 = KTb[(size_t)m * 128];
            float k1 = KTb[(size_t)(m + 1) * 128];
            float k2 = KTb[(size_t)(m + 2) * 128];
            float k3 = KTb[(size_t)(m + 3) * 128];
            #pragma unroll
            for (int r = 0; r < 4; ++r) {
                float4 qv = *(const float4*)&qs[rg + r][m];
                acc[r] += qv.x * k0 + qv.y * k1 + qv.z * k2 + qv.w * k3;
            }
        }
        #pragma unroll
        for (int r = 0; r < 4; ++r) ws[rg + r][kk] = acc[r] * 0.125f;
    }
    __syncthreads();
    {
        const int r = t >> 5, j = t & 31;
        float4 v0 = *(float4*)&ws[r][j * 4];
        float mx = fmaxf(fmaxf(v0.x, v0.y), fmaxf(v0.z, v0.w));
        #pragma unroll
        for (int o = 1; o < 32; o <<= 1) mx = fmaxf(mx, __shfl_xor(mx, o));
        v0.x = expf(v0.x - mx); v0.y = expf(v0.y - mx);
        v0.z = expf(v0.z - mx); v0.w = expf(v0.w - mx);
        float sum = v0.x + v0.y + v0.z + v0.w;
        #pragma unroll
        for (int o = 1; o < 32; o <<= 1) sum += __shfl_xor(sum, o);
        *(float4*)&ws[r][j * 4] = v0;
        if (j == 0) denom[r] = sum;
    }
    __syncthreads();
    {
        const int w = t >> 6, lane = t & 63;
        const int c0 = lane * 4;
        const float* vb = VWo + (size_t)b * 128 * D_INN + c0;
        float acc[2][4] = {};
        #pragma unroll 8
        for (int k = 0; k < 128; k += 2) {
            float4 vw0 = *(const float4*)&vb[(size_t)k * D_INN];
            float4 vw1 = *(const float4*)&vb[(size_t)(k + 1) * D_INN];
            #pragma unroll
            for (int r = 0; r < 2; ++r) {
                float wk0 = ws[w * 2 + r][k];
                float wk1 = ws[w * 2 + r][k + 1];
                acc[r][0] += wk0 * vw0.x + wk1 * vw1.x;
                acc[r][1] += wk0 * vw0.y + wk1 * vw1.y;
                acc[r][2] += wk0 * vw0.z + wk1 * vw1.z;
                acc[r][3] += wk0 * vw0.w + wk1 * vw1.w;
            }
        }
        float4 bov = *(const float4*)&bo[c0];
        #pragma unroll
        for (int r = 0; r < 2; ++r) {
            size_t rr = rowbase + w * 2 + r;
            float dn = 1.f / denom[w * 2 + r];
            float4 yv = *(const float4*)&y[rr * D_INN + c0];
            float4 xv = *(const float4*)&x[rr * D_INN + c0];
            float4 Ev = *(const float4*)&proj[rr * NTOT + 192 + c0];
            float4 Fv = *(const float4*)&proj[rr * NTOT + 448 + c0];
            float4 o;
            o.x = yv.x + (acc[r][0] * dn + bov.x) * Ev.x + xv.x * Fv.x;
            o.y = yv.y + (acc[r][1] * dn + bov.y) * Ev.y + xv.y * Fv.y;
            o.z = yv.z + (acc[r][2] * dn + bov.z) * Ev.z + xv.z * Fv.z;
            o.w = yv.w + (acc[r][3] * dn + bov.w) * Ev.w + xv.w * Fv.w;
            *(float4*)&out[rr * D_INN + c0] = o;
        }
    }
}

extern "C" void kernel_launch(void* const* d_in, const int* in_sizes, int n_in,
                              void* d_out, int out_size, void* d_ws, size_t ws_size,
                              hipStream_t stream) {
    const float* x    = (const float*)d_in[0];
    const float* Wx   = (const float*)d_in[1];
    const float* Wdt  = (const float*)d_in[2];
    const float* bdt  = (const float*)d_in[3];
    const float* Wdtl = (const float*)d_in[4];
    const float* bdtl = (const float*)d_in[5];
    const float* A    = (const float*)d_in[6];
    const float* Dp   = (const float*)d_in[7];
    const float* Wq   = (const float*)d_in[8];
    const float* bq   = (const float*)d_in[9];
    const float* Wk   = (const float*)d_in[10];
    const float* bk   = (const float*)d_in[11];
    const float* Wv   = (const float*)d_in[12];
    const float* bv   = (const float*)d_in[13];
    const float* Wo   = (const float*)d_in[14];
    const float* bo   = (const float*)d_in[15];
    float* out = (float*)d_out;
    float* ws = (float*)d_ws;

    float* proj    = ws;                                    // 4096*864
    float* deltaT  = proj + (size_t)NROWS * NTOT;           // [b][d][l]
    float* deltalT = deltaT + (size_t)NROWS * D_INN;        // [b][d][l]
    float* pT0     = deltalT + (size_t)NROWS * D_INN;       // [b][d][l] δ0·u
    float* pT1     = pT0 + (size_t)NROWS * D_INN;           // [b][d][l] δ1·u
    float* csum0   = pT1 + (size_t)NROWS * D_INN;           // [b][d][chunk]
    float* csum1   = csum0 + (size_t)BB * D_INN * NCHUNK;
    float* yb      = csum1 + (size_t)BB * D_INN * NCHUNK;   // 4096*256
    float* mem     = yb + (size_t)NROWS * D_INN;            // 2*128*256
    float* KTb     = mem + (size_t)BB * 128 * D_INN;        // 2*128*128
    float* Qbuf    = KTb + (size_t)BB * 128 * D_MEMM;       // 4*16*256*64
    float* SDbuf   = Qbuf + (size_t)4 * SEG * D_INN * 64;   // 4*16*256
    float* cumd    = SDbuf + (size_t)4 * SEG * D_INN;       // 2*16*8*256
    float* VWo     = cumd + (size_t)BB * SEG * 8 * D_INN;   // 2*128*256
    float* xT      = VWo + (size_t)BB * 128 * D_INN;        // [b][d][l]
    float* packed  = xT + (size_t)NROWS * D_INN;            // 3*2*256*64*8

    hipLaunchKernelGGL(k_gemm, dim3(14, 64), dim3(256), 0, stream, x, Wx, Wq, bq, proj, packed);
    hipLaunchKernelGGL(k_prep, dim3(256, 2), dim3(256), 0, stream,
                       x, proj, Wdt, bdt, Wdtl, bdtl, deltaT, deltalT,
                       pT0, pT1, csum0, csum1, xT);
    hipLaunchKernelGGL(k_scanA, dim3(64, 2, 16), dim3(256), 0, stream,
                       packed, A, deltaT, deltalT, pT0, pT1, csum0, csum1,
                       Qbuf, SDbuf, cumd, mem);
    hipLaunchKernelGGL(k_scanBC, dim3(64, 2, 16), dim3(256), 0, stream,
                       xT, packed, A, Dp, deltaT, pT0, Qbuf, SDbuf, cumd, yb, mem);
    hipLaunchKernelGGL(k_kvwo, dim3(128, 2), dim3(128), 0, stream,
                       mem, Wk, bk, Wv, bv, Wo, KTb, VWo);
    hipLaunchKernelGGL(k_attn, dim3(LL / 8, 2), dim3(256), 0, stream,
                       x, proj, yb, KTb, VWo, bo, out);
}

// Round 17
// 193.480 us; speedup vs baseline: 1.0204x; 1.0204x over previous
//
#include <hip/hip_runtime.h>
#include <math.h>

#define D_INN 256
#define D_HID 64
#define DTR 16
#define D_MEMM 128
#define BB 2
#define LL 2048
#define NROWS (BB*LL)   // 4096
#define NPROJ 736
#define NTOT 864        // 736 proj cols + 128 Q cols
#define SEG 16
#define SEGLEN (LL/SEG) // 128
#define NCHUNK (LL/8)   // 256 8-step chunks per batch

typedef __attribute__((ext_vector_type(8))) short short8v;
typedef __attribute__((ext_vector_type(4))) float float4v;

static __device__ __forceinline__ unsigned short f2bf(float f) {
    unsigned int u = __float_as_uint(f);
    u += 0x7fff + ((u >> 16) & 1);   // RNE
    return (unsigned short)(u >> 16);
}

// raw v_exp_f32 (1 instr). Safe: scan args are ~1e-3 (delta ~ e^-11, |A| <= 256).
static __device__ __forceinline__ float ex2(float x) {
    return __builtin_amdgcn_exp2f(x);
}

// packed index: (((g*BB + b)*NCHUNK + chunk)*64 + n)*8 + li   (g: 0=B, 1=Bl, 2=C)
#define PK(g, b, chunk, n, li) (((((size_t)(g)*BB + (b)) * NCHUNK + (chunk)) * 64 + (n)) * 8 + (li))

// ---------------- Kernel 1: proj = x @ [W_xproj | W_Q] (+b_Q), bf16 MFMA ----------------
__global__ __launch_bounds__(256) void k_gemm(const float* __restrict__ x,
        const float* __restrict__ Wx, const float* __restrict__ Wq,
        const float* __restrict__ bq, float* __restrict__ proj,
        float* __restrict__ packed) {
    __shared__ unsigned short As[64][40];
    __shared__ unsigned short Bs[64][40];
    const int t = threadIdx.x;
    const int lane = t & 63, w = t >> 6;
    const int wr = w >> 1, wc = w & 1;
    const int row0 = blockIdx.y * 64, col0 = blockIdx.x * 64;

    float4v acc[2][2];
    #pragma unroll
    for (int i = 0; i < 2; i++)
        #pragma unroll
        for (int j = 0; j < 2; j++) acc[i][j] = (float4v)0.f;

    const int ar = t >> 2, akq = (t & 3) * 8;
    const int bk = t >> 3, bcq = (t & 7) * 8;

    for (int k0 = 0; k0 < D_INN; k0 += 32) {
        float4 a0 = *(const float4*)&x[(size_t)(row0 + ar) * D_INN + k0 + akq];
        float4 a1 = *(const float4*)&x[(size_t)(row0 + ar) * D_INN + k0 + akq + 4];
        float4 b0 = {}, b1 = {};
        int col = col0 + bcq;
        if (col + 8 <= NPROJ) {
            b0 = *(const float4*)&Wx[(size_t)(k0 + bk) * NPROJ + col];
            b1 = *(const float4*)&Wx[(size_t)(k0 + bk) * NPROJ + col + 4];
        } else if (col < NTOT) {
            b0 = *(const float4*)&Wq[(size_t)(k0 + bk) * D_MEMM + (col - NPROJ)];
            b1 = *(const float4*)&Wq[(size_t)(k0 + bk) * D_MEMM + (col - NPROJ) + 4];
        }
        __syncthreads();
        {
            unsigned short av[8] = { f2bf(a0.x), f2bf(a0.y), f2bf(a0.z), f2bf(a0.w),
                                     f2bf(a1.x), f2bf(a1.y), f2bf(a1.z), f2bf(a1.w) };
            *(short8v*)&As[ar][akq] = *(short8v*)av;
            Bs[bcq + 0][bk] = f2bf(b0.x); Bs[bcq + 1][bk] = f2bf(b0.y);
            Bs[bcq + 2][bk] = f2bf(b0.z); Bs[bcq + 3][bk] = f2bf(b0.w);
            Bs[bcq + 4][bk] = f2bf(b1.x); Bs[bcq + 5][bk] = f2bf(b1.y);
            Bs[bcq + 6][bk] = f2bf(b1.z); Bs[bcq + 7][bk] = f2bf(b1.w);
        }
        __syncthreads();
        short8v af[2], bf[2];
        const int fr = lane & 15, fk = (lane >> 4) * 8;
        af[0] = *(short8v*)&As[wr * 32 + fr][fk];
        af[1] = *(short8v*)&As[wr * 32 + 16 + fr][fk];
        bf[0] = *(short8v*)&Bs[wc * 32 + fr][fk];
        bf[1] = *(short8v*)&Bs[wc * 32 + 16 + fr][fk];
        #pragma unroll
        for (int i = 0; i < 2; i++)
            #pragma unroll
            for (int j = 0; j < 2; j++)
                acc[i][j] = __builtin_amdgcn_mfma_f32_16x16x32_bf16(af[i], bf[j], acc[i][j], 0, 0, 0);
    }
    #pragma unroll
    for (int i = 0; i < 2; i++)
        #pragma unroll
        for (int j = 0; j < 2; j++) {
            int cc = col0 + wc * 32 + j * 16 + (lane & 15);
            int rr0 = row0 + wr * 32 + i * 16 + (lane >> 4) * 4;
            if (cc < 192) {   // B / Bl / C -> packed layout
                int g = cc >> 6, n = cc & 63;
                int bb = rr0 >> 11, l = rr0 & (LL - 1);
                float4 pk = make_float4(acc[i][j][0], acc[i][j][1], acc[i][j][2], acc[i][j][3]);
                *(float4*)&packed[PK(g, bb, l >> 3, n, l & 7)] = pk;
            } else {
                #pragma unroll
                for (int e = 0; e < 4; e++) {
                    float v = acc[i][j][e];
                    if (cc >= NPROJ) v += bq[cc - NPROJ];
                    proj[(size_t)(rr0 + e) * NTOT + cc] = v;
                }
            }
        }
}

// ---------------- Kernel 2: prep = {delta/p/csum transposed | x transpose} ----------------
__global__ __launch_bounds__(256) void k_prep(const float* __restrict__ x,
        const float* __restrict__ proj,
        const float* __restrict__ Wdt, const float* __restrict__ bdt,
        const float* __restrict__ Wdtl, const float* __restrict__ bdtl,
        float* __restrict__ deltaT, float* __restrict__ deltalT,
        float* __restrict__ pT0, float* __restrict__ pT1,
        float* __restrict__ csum0, float* __restrict__ csum1,
        float* __restrict__ xT) {
    __shared__ float sh[64 * 66];
    const int t = threadIdx.x;
    if (blockIdx.y == 0) {
        float (*sdt)[17]  = (float(*)[17])sh;
        float (*sdtl)[17] = (float(*)[17])(sh + 16 * 17);
        const int r0 = blockIdx.x * 16;
        const int b = r0 >> 11, l0 = r0 & (LL - 1);
        {
            int r = t >> 4, c = t & 15;
            sdt[r][c]  = proj[(size_t)(r0 + r) * NTOT + 704 + c];
            sdtl[r][c] = proj[(size_t)(r0 + r) * NTOT + 720 + c];
        }
        __syncthreads();
        float w1[DTR], w2[DTR];
        #pragma unroll
        for (int r = 0; r < DTR; r++) {
            w1[r] = Wdt[r * D_INN + t];
            w2[r] = Wdtl[r * D_INN + t];
        }
        const float b1 = bdt[t], b2 = bdtl[t];
        float o1[16], o2[16], q1[16], q2[16];
        #pragma unroll
        for (int row = 0; row < 16; ++row) {
            float a1 = b1, a2 = b2;
            #pragma unroll
            for (int r = 0; r < DTR; r++) {
                a1 += sdt[row][r] * w1[r];
                a2 += sdtl[row][r] * w2[r];
            }
            o1[row] = (a1 > 20.f) ? a1 : log1pf(expf(a1));
            o2[row] = (a2 > 20.f) ? a2 : log1pf(expf(a2));
            float xv = x[(size_t)(r0 + row) * D_INN + t];
            q1[row] = o1[row] * xv;
            q2[row] = o2[row] * xv;
        }
        float* d1 = &deltaT[((size_t)b * D_INN + t) * LL + l0];
        float* d2 = &deltalT[((size_t)b * D_INN + t) * LL + l0];
        float* p1 = &pT0[((size_t)b * D_INN + t) * LL + l0];
        float* p2 = &pT1[((size_t)b * D_INN + t) * LL + l0];
        #pragma unroll
        for (int j = 0; j < 16; j += 4) {
            *(float4*)&d1[j] = make_float4(o1[j], o1[j+1], o1[j+2], o1[j+3]);
            *(float4*)&d2[j] = make_float4(o2[j], o2[j+1], o2[j+2], o2[j+3]);
            *(float4*)&p1[j] = make_float4(q1[j], q1[j+1], q1[j+2], q1[j+3]);
            *(float4*)&p2[j] = make_float4(q2[j], q2[j+1], q2[j+2], q2[j+3]);
        }
        // per-chunk delta sums (2 chunks per thread)
        float c0a = 0.f, c0b = 0.f, c1a = 0.f, c1b = 0.f;
        #pragma unroll
        for (int j = 0; j < 8; ++j) { c0a += o1[j]; c0b += o1[8 + j];
                                      c1a += o2[j]; c1b += o2[8 + j]; }
        size_t cbase = ((size_t)b * D_INN + t) * NCHUNK + (l0 >> 3);
        csum0[cbase] = c0a; csum0[cbase + 1] = c0b;
        csum1[cbase] = c1a; csum1[cbase + 1] = c1b;
    } else {
        float (*tile)[65] = (float(*)[65])sh;
        const int bx = blockIdx.x;
        const int lt = (bx & 31) * 64, dt = ((bx >> 5) & 3) * 64, b = bx >> 7;
        const int c = t & 63, rg = (t >> 6) * 16;
        #pragma unroll
        for (int j = 0; j < 16; ++j)
            tile[rg + j][c] = x[((size_t)b * LL + lt + rg + j) * D_INN + dt + c];
        __syncthreads();
        #pragma unroll
        for (int j = 0; j < 16; ++j)
            xT[((size_t)b * D_INN + dt + rg + j) * LL + lt + c] = tile[c][rg + j];
    }
}

// ---------------- Kernel 3A: both scans' pass 1 — native exp2, hoisted precompute ----
// grid (64, 2, 16); block 256 = 4 waves; wave w -> d = d0+w, lane n.
__global__ __launch_bounds__(256) void k_scanA(
        const float* __restrict__ packed, const float* __restrict__ A,
        const float* __restrict__ deltaT, const float* __restrict__ deltalT,
        const float* __restrict__ pT0, const float* __restrict__ pT1,
        const float* __restrict__ csum0, const float* __restrict__ csum1,
        float* __restrict__ Qbuf, float* __restrict__ SDbuf,
        float* __restrict__ cumd, float* __restrict__ mem) {
    const int t = threadIdx.x, w = t >> 6, n = t & 63;
    const int b = blockIdx.y, seg = blockIdx.z;
    const int d = blockIdx.x * 4 + w;
    const float Aln = A[d * D_HID + n] * 1.44269504f;
    const size_t base = ((size_t)b * D_INN + d) * LL + seg * SEGLEN;
    const float* dT0 = deltaT + base;
    const float* dT1 = deltalT + base;
    const float* pp0 = pT0 + base;
    const float* pp1 = pT1 + base;
    const float* Bp0 = packed + PK(0, b, seg * 16, 0, 0);
    const float* Bp1 = packed + PK(1, b, seg * 16, 0, 0);
    const size_t cbase = ((size_t)b * D_INN + d) * NCHUNK + seg * 16;

    float cum[8], part[8];
    float s0 = 0.f, s1 = 0.f, sd1 = 0.f;

    for (int c = 0; c < 16; ++c) {
        // wave-uniform loads (same address across lanes -> L1 broadcast)
        float4 d0a = *(const float4*)&dT0[c * 8], d0b = *(const float4*)&dT0[c * 8 + 4];
        float4 d1a = *(const float4*)&dT1[c * 8], d1b = *(const float4*)&dT1[c * 8 + 4];
        float4 p0a = *(const float4*)&pp0[c * 8], p0b = *(const float4*)&pp0[c * 8 + 4];
        float4 p1a = *(const float4*)&pp1[c * 8], p1b = *(const float4*)&pp1[c * 8 + 4];
        // per-lane B loads
        float4 B00 = *(const float4*)&Bp0[((size_t)c * 64 + n) * 8];
        float4 B01 = *(const float4*)&Bp0[((size_t)c * 64 + n) * 8 + 4];
        float4 B10 = *(const float4*)&Bp1[((size_t)c * 64 + n) * 8];
        float4 B11 = *(const float4*)&Bp1[((size_t)c * 64 + n) * 8 + 4];
        float dv0[8] = {d0a.x, d0a.y, d0a.z, d0a.w, d0b.x, d0b.y, d0b.z, d0b.w};
        float dv1[8] = {d1a.x, d1a.y, d1a.z, d1a.w, d1b.x, d1b.y, d1b.z, d1b.w};
        float pv0[8] = {p0a.x, p0a.y, p0a.z, p0a.w, p0b.x, p0b.y, p0b.z, p0b.w};
        float pv1[8] = {p1a.x, p1a.y, p1a.z, p1a.w, p1b.x, p1b.y, p1b.z, p1b.w};
        float Bv0[8] = {B00.x, B00.y, B00.z, B00.w, B01.x, B01.y, B01.z, B01.w};
        float Bv1[8] = {B10.x, B10.y, B10.z, B10.w, B11.x, B11.y, B11.z, B11.w};
        // hoisted: dA and p*B outside the serial chains
        float dA0[8], dA1[8], pB0[8], pB1[8];
        #pragma unroll
        for (int li = 0; li < 8; ++li) {
            dA0[li] = ex2(dv0[li] * Aln);
            dA1[li] = ex2(dv1[li] * Aln);
            pB0[li] = pv0[li] * Bv0[li];
            pB1[li] = pv1[li] * Bv1[li];
        }
        // serial chains (pure fmaf)
        s1 = fmaf(dA1[0], s1, pB1[0]);
        if ((c & 1) == 0) {
            float v = s1;
            #pragma unroll
            for (int off = 32; off >= 1; off >>= 1) v += __shfl_xor(v, off);
            part[c >> 1] = v;
            cum[c >> 1] = sd1 + dv1[0];
        }
        #pragma unroll
        for (int li = 1; li < 8; ++li) s1 = fmaf(dA1[li], s1, pB1[li]);
        #pragma unroll
        for (int li = 0; li < 8; ++li) s0 = fmaf(dA0[li], s0, pB0[li]);
        sd1 += csum1[cbase + c];
    }
    // sd0: total segment delta sum from chunk sums
    float sd0 = 0.f;
    {
        float4 ca = *(const float4*)&csum0[cbase];
        float4 cb = *(const float4*)&csum0[cbase + 4];
        float4 cc = *(const float4*)&csum0[cbase + 8];
        float4 cd = *(const float4*)&csum0[cbase + 12];
        sd0 = ((ca.x + ca.y) + (ca.z + ca.w)) + ((cb.x + cb.y) + (cb.z + cb.w))
            + ((cc.x + cc.y) + (cc.z + cc.w)) + ((cd.x + cd.y) + (cd.z + cd.w));
    }

    Qbuf[(((size_t)b * SEG + seg) * D_INN + d) * 64 + n] = s0;
    Qbuf[(((size_t)(2 + b) * SEG + seg) * D_INN + d) * 64 + n] = s1;
    if (n == 0) {
        SDbuf[((size_t)b * SEG + seg) * D_INN + d] = sd0;
        SDbuf[((size_t)(2 + b) * SEG + seg) * D_INN + d] = sd1;
        #pragma unroll
        for (int ck = 0; ck < 8; ++ck) {
            mem[((size_t)b * 128 + seg * 8 + ck) * D_INN + d] = part[ck];
            cumd[(((size_t)b * SEG + seg) * 8 + ck) * D_INN + d] = cum[ck];
        }
    }
}

// ---------------- Kernel 3B: prefix + pass 2 (scan0) + mem corrections (scan1) ----------
__global__ __launch_bounds__(256) void k_scanBC(const float* __restrict__ xT,
        const float* __restrict__ packed, const float* __restrict__ A,
        const float* __restrict__ Dp, const float* __restrict__ deltaT,
        const float* __restrict__ pT0,
        const float* __restrict__ Qbuf, const float* __restrict__ SDbuf,
        const float* __restrict__ cumd,
        float* __restrict__ y, float* __restrict__ mem) {
    __shared__ float rbuf[4][8][65];
    const int t = threadIdx.x, w = t >> 6, n = t & 63;
    const int b = blockIdx.y, seg = blockIdx.z;
    const int d = blockIdx.x * 4 + w;
    const int lr = n & 7, rli = n >> 3, g = n & 7;
    const float Aln = A[d * D_HID + n] * 1.44269504f;
    const float Dpv = Dp[d];
    const size_t rowbase = (size_t)b * LL + (size_t)seg * SEGLEN;
    const size_t base = ((size_t)b * D_INN + d) * LL + seg * SEGLEN;
    const float* uT  = xT + base;
    const float* dT0 = deltaT + base;
    const float* pp0 = pT0 + base;
    const float* Bp = packed + PK(0, b, seg * 16, 0, 0);
    const float* Cp = packed + PK(2, b, seg * 16, 0, 0);

    // prefix s_in for both scans
    float sin0 = 0.f, sin1 = 0.f;
    for (int k = 0; k < seg; ++k) {
        float sdk0 = SDbuf[((size_t)b * SEG + k) * D_INN + d];
        float qk0  = Qbuf[(((size_t)b * SEG + k) * D_INN + d) * 64 + n];
        sin0 = fmaf(ex2(sdk0 * Aln), sin0, qk0);
        float sdk1 = SDbuf[((size_t)(2 + b) * SEG + k) * D_INN + d];
        float qk1  = Qbuf[(((size_t)(2 + b) * SEG + k) * D_INN + d) * 64 + n];
        sin1 = fmaf(ex2(sdk1 * Aln), sin1, qk1);
    }

    // mem corrections for scan1 (seg > 0)
    if (seg > 0) {
        #pragma unroll
        for (int ck = 0; ck < 8; ++ck) {
            float cum = cumd[(((size_t)b * SEG + seg) * 8 + ck) * D_INN + d];
            float v = ex2(cum * Aln) * sin1;
            #pragma unroll
            for (int off = 32; off >= 1; off >>= 1) v += __shfl_xor(v, off);
            if (n == 0) mem[((size_t)b * 128 + seg * 8 + ck) * D_INN + d] += v;
        }
    }

    // pass 2 for scan0: wave-uniform δ/p loads, ILP precompute
    float s = sin0;
    for (int c = 0; c < 16; ++c) {
        const size_t l0 = rowbase + c * 8;
        float4 d0a = *(const float4*)&dT0[c * 8], d0b = *(const float4*)&dT0[c * 8 + 4];
        float4 p0a = *(const float4*)&pp0[c * 8], p0b = *(const float4*)&pp0[c * 8 + 4];
        float uvl = uT[c * 8 + lr];   // per-lane, for the y epilogue shfl
        float4 B0 = *(const float4*)&Bp[((size_t)c * 64 + n) * 8];
        float4 B1 = *(const float4*)&Bp[((size_t)c * 64 + n) * 8 + 4];
        float4 C0 = *(const float4*)&Cp[((size_t)c * 64 + n) * 8];
        float4 C1 = *(const float4*)&Cp[((size_t)c * 64 + n) * 8 + 4];
        float dv[8] = {d0a.x, d0a.y, d0a.z, d0a.w, d0b.x, d0b.y, d0b.z, d0b.w};
        float pv[8] = {p0a.x, p0a.y, p0a.z, p0a.w, p0b.x, p0b.y, p0b.z, p0b.w};
        float Bv[8] = {B0.x, B0.y, B0.z, B0.w, B1.x, B1.y, B1.z, B1.w};
        float Cv[8] = {C0.x, C0.y, C0.z, C0.w, C1.x, C1.y, C1.z, C1.w};
        float dAr[8], pBr[8];
        #pragma unroll
        for (int li = 0; li < 8; ++li) {
            dAr[li] = ex2(dv[li] * Aln);
            pBr[li] = pv[li] * Bv[li];
        }
        #pragma unroll
        for (int li = 0; li < 8; ++li) {
            s = fmaf(dAr[li], s, pBr[li]);
            rbuf[w][li][n] = s * Cv[li];
        }
        float acc = 0.f;
        #pragma unroll
        for (int j = 0; j < 8; ++j) acc += rbuf[w][rli][g * 8 + j];
        acc += __shfl_xor(acc, 1);
        acc += __shfl_xor(acc, 2);
        acc += __shfl_xor(acc, 4);
        float uv = __shfl(uvl, rli);   // outside the guard (all lanes active)
        if (g == 0) {
            y[(l0 + rli) * D_INN + d] = acc + uv * Dpv;
        }
    }
}

// ---------------- Kernel 4: fused K^T, V, VWo per memory row ----------------
__global__ __launch_bounds__(128) void k_kvwo(const float* __restrict__ mem,
        const float* __restrict__ Wk, const float* __restrict__ bk,
        const float* __restrict__ Wv, const float* __restrict__ bv,
        const float* __restrict__ Wo,
        float* __restrict__ KT, float* __restrict__ VWo) {
    __shared__ float mrow[256];
    __shared__ float vrow[128];
    const int k = blockIdx.x, b = blockIdx.y;
    const int t = threadIdx.x;
    const float* mr = mem + ((size_t)b * 128 + k) * D_INN;
    mrow[t] = mr[t];
    mrow[t + 128] = mr[t + 128];
    __syncthreads();
    float aK = bk[t], aV = bv[t];
    for (int dd = 0; dd < D_INN; dd++) {
        float m = mrow[dd];
        aK += m * Wk[dd * D_MEMM + t];
        aV += m * Wv[dd * D_MEMM + t];
    }
    KT[((size_t)b * 128 + t) * 128 + k] = aK;   // transposed store
    vrow[t] = aV;
    __syncthreads();
    float a0 = 0.f, a1 = 0.f;
    for (int m = 0; m < 128; ++m) {
        float vm = vrow[m];
        a0 += vm * Wo[(size_t)m * D_INN + t];
        a1 += vm * Wo[(size_t)m * D_INN + t + 128];
    }
    VWo[((size_t)b * 128 + k) * D_INN + t] = a0;
    VWo[((size_t)b * 128 + k) * D_INN + t + 128] = a1;
}

// ---------------- Kernel 5: attention + epilogue, 8 rows per block ----------------
__global__ __launch_bounds__(256) void k_attn(const float* __restrict__ x,
        const float* __restrict__ proj, const float* __restrict__ y,
        const float* __restrict__ KT, const float* __restrict__ VWo,
        const float* __restrict__ bo, float* __restrict__ out) {
    __shared__ float qs[8][132];
    __shared__ float ws[8][132];
    __shared__ float denom[8];
    const int t = threadIdx.x;
    const int b = blockIdx.y;
    const int r0 = blockIdx.x * 8;
    const size_t rowbase = (size_t)b * LL + r0;
    {
        int r = t >> 5, c4 = (t & 31) * 4;
        *(float4*)&qs[r][c4] = *(const float4*)&proj[(rowbase + r) * NTOT + NPROJ + c4];
    }
    __syncthreads();
    {
        const int kk = t & 127, rg = (t >> 7) * 4;
        const float* KTb = KT + (size_t)b * 128 * 128 + kk;
        float acc[4] = {};
        #pragma unroll 8
        for (int m = 0; m < 128; m += 4) {
            float k0 = KTb[(size_t)m * 128];
            float k1 = KTb[(size_t)(m + 1) * 128];
            float k2 = KTb[(size_t)(m + 2) * 128];
            float k3 = KTb[(size_t)(m + 3) * 128];
            #pragma unroll
            for (int r = 0; r < 4; ++r) {
                float4 qv = *(const float4*)&qs[rg + r][m];
                acc[r] += qv.x * k0 + qv.y * k1 + qv.z * k2 + qv.w * k3;
            }
        }
        #pragma unroll
        for (int r = 0; r < 4; ++r) ws[rg + r][kk] = acc[r] * 0.125f;
    }
    __syncthreads();
    {
        const int r = t >> 5, j = t & 31;
        float4 v0 = *(float4*)&ws[r][j * 4];
        float mx = fmaxf(fmaxf(v0.x, v0.y), fmaxf(v0.z, v0.w));
        #pragma unroll
        for (int o = 1; o < 32; o <<= 1) mx = fmaxf(mx, __shfl_xor(mx, o));
        v0.x = expf(v0.x - mx); v0.y = expf(v0.y - mx);
        v0.z = expf(v0.z - mx); v0.w = expf(v0.w - mx);
        float sum = v0.x + v0.y + v0.z + v0.w;
        #pragma unroll
        for (int o = 1; o < 32; o <<= 1) sum += __shfl_xor(sum, o);
        *(float4*)&ws[r][j * 4] = v0;
        if (j == 0) denom[r] = sum;
    }
    __syncthreads();
    {
        const int w = t >> 6, lane = t & 63;
        const int c0 = lane * 4;
        const float* vb = VWo + (size_t)b * 128 * D_INN + c0;
        float acc[2][4] = {};
        #pragma unroll 8
        for (int k = 0; k < 128; k += 2) {
            float4 vw0 = *(const float4*)&vb[(size_t)k * D_INN];
            float4 vw1 = *(const float4*)&vb[(size_t)(k + 1) * D_INN];
            #pragma unroll
            for (int r = 0; r < 2; ++r) {
                float wk0 = ws[w * 2 + r][k];
                float wk1 = ws[w * 2 + r][k + 1];
                acc[r][0] += wk0 * vw0.x + wk1 * vw1.x;
                acc[r][1] += wk0 * vw0.y + wk1 * vw1.y;
                acc[r][2] += wk0 * vw0.z + wk1 * vw1.z;
                acc[r][3] += wk0 * vw0.w + wk1 * vw1.w;
            }
        }
        float4 bov = *(const float4*)&bo[c0];
        #pragma unroll
        for (int r = 0; r < 2; ++r) {
            size_t rr = rowbase + w * 2 + r;
            float dn = 1.f / denom[w * 2 + r];
            float4 yv = *(const float4*)&y[rr * D_INN + c0];
            float4 xv = *(const float4*)&x[rr * D_INN + c0];
            float4 Ev = *(const float4*)&proj[rr * NTOT + 192 + c0];
            float4 Fv = *(const float4*)&proj[rr * NTOT + 448 + c0];
            float4 o;
            o.x = yv.x + (acc[r][0] * dn + bov.x) * Ev.x + xv.x * Fv.x;
            o.y = yv.y + (acc[r][1] * dn + bov.y) * Ev.y + xv.y * Fv.y;
            o.z = yv.z + (acc[r][2] * dn + bov.z) * Ev.z + xv.z * Fv.z;
            o.w = yv.w + (acc[r][3] * dn + bov.w) * Ev.w + xv.w * Fv.w;
            *(float4*)&out[rr * D_INN + c0] = o;
        }
    }
}

extern "C" void kernel_launch(void* const* d_in, const int* in_sizes, int n_in,
                              void* d_out, int out_size, void* d_ws, size_t ws_size,
                              hipStream_t stream) {
    const float* x    = (const float*)d_in[0];
    const float* Wx   = (const float*)d_in[1];
    const float* Wdt  = (const float*)d_in[2];
    const float* bdt  = (const float*)d_in[3];
    const float* Wdtl = (const float*)d_in[4];
    const float* bdtl = (const float*)d_in[5];
    const float* A    = (const float*)d_in[6];
    const float* Dp   = (const float*)d_in[7];
    const float* Wq   = (const float*)d_in[8];
    const float* bq   = (const float*)d_in[9];
    const float* Wk   = (const float*)d_in[10];
    const float* bk   = (const float*)d_in[11];
    const float* Wv   = (const float*)d_in[12];
    const float* bv   = (const float*)d_in[13];
    const float* Wo   = (const float*)d_in[14];
    const float* bo   = (const float*)d_in[15];
    float* out = (float*)d_out;
    float* ws = (float*)d_ws;

    float* proj    = ws;                                    // 4096*864
    float* deltaT  = proj + (size_t)NROWS * NTOT;           // [b][d][l]
    float* deltalT = deltaT + (size_t)NROWS * D_INN;        // [b][d][l]
    float* pT0     = deltalT + (size_t)NROWS * D_INN;       // [b][d][l] δ0·u
    float* pT1     = pT0 + (size_t)NROWS * D_INN;           // [b][d][l] δ1·u
    float* csum0   = pT1 + (size_t)NROWS * D_INN;           // [b][d][chunk]
    float* csum1   = csum0 + (size_t)BB * D_INN * NCHUNK;
    float* yb      = csum1 + (size_t)BB * D_INN * NCHUNK;   // 4096*256
    float* mem     = yb + (size_t)NROWS * D_INN;            // 2*128*256
    float* KTb     = mem + (size_t)BB * 128 * D_INN;        // 2*128*128
    float* Qbuf    = KTb + (size_t)BB * 128 * D_MEMM;       // 4*16*256*64
    float* SDbuf   = Qbuf + (size_t)4 * SEG * D_INN * 64;   // 4*16*256
    float* cumd    = SDbuf + (size_t)4 * SEG * D_INN;       // 2*16*8*256
    float* VWo     = cumd + (size_t)BB * SEG * 8 * D_INN;   // 2*128*256
    float* xT      = VWo + (size_t)BB * 128 * D_INN;        // [b][d][l]
    float* packed  = xT + (size_t)NROWS * D_INN;            // 3*2*256*64*8

    hipLaunchKernelGGL(k_gemm, dim3(14, 64), dim3(256), 0, stream, x, Wx, Wq, bq, proj, packed);
    hipLaunchKernelGGL(k_prep, dim3(256, 2), dim3(256), 0, stream,
                       x, proj, Wdt, bdt, Wdtl, bdtl, deltaT, deltalT,
                       pT0, pT1, csum0, csum1, xT);
    hipLaunchKernelGGL(k_scanA, dim3(64, 2, 16), dim3(256), 0, stream,
                       packed, A, deltaT, deltalT, pT0, pT1, csum0, csum1,
                       Qbuf, SDbuf, cumd, mem);
    hipLaunchKernelGGL(k_scanBC, dim3(64, 2, 16), dim3(256), 0, stream,
                       xT, packed, A, Dp, deltaT, pT0, Qbuf, SDbuf, cumd, yb, mem);
    hipLaunchKernelGGL(k_kvwo, dim3(128, 2), dim3(128), 0, stream,
                       mem, Wk, bk, Wv, bv, Wo, KTb, VWo);
    hipLaunchKernelGGL(k_attn, dim3(LL / 8, 2), dim3(256), 0, stream,
                       x, proj, yb, KTb, VWo, bo, out);
}